// Round 1
// baseline (23158.025 us; speedup 1.0000x reference)
//
#include <hip/hip_runtime.h>
#include <hip/hip_bf16.h>
#include <cstdint>
#include <cstddef>

// Bidirectional 2-layer LSTM, B=128 T=2048 I=H=O=256.
// Output = FC([h_fwd_top(T-1) | h_bwd_top(after ONE step on x[T-1])]).
// Forward: 2049 step kernels (layer wavefront: kernel k does L0 step k and L1 step k-1).
// Backward: single step per layer with zero state (outs_rev[0] only!).

#define B_   128
#define T_   2048
#define I_   256
#define H_   256
#define G4_  1024          // 4*H
#define BH_  (B_*H_)       // 32768

using bf16   = __bf16;
using bf16x8 = __attribute__((ext_vector_type(8))) __bf16;
using f32x4  = __attribute__((ext_vector_type(4))) float;
using f32x8  = __attribute__((ext_vector_type(8))) float;

__device__ __forceinline__ float sigm(float v) { return 1.0f / (1.0f + expf(-v)); }

// Convert weights to bf16, precompute bias sums. grid 2048 x 256.
__global__ void prep_kernel(const float* __restrict__ Wxh, const float* __restrict__ Whh,
                            const float* __restrict__ bxh, const float* __restrict__ bhh,
                            bf16* __restrict__ Wxbf, bf16* __restrict__ Whbf,
                            float* __restrict__ bsum) {
    int t = blockIdx.x * 256 + threadIdx.x;   // 0 .. 524287 (= 2*1024*256)
    Wxbf[t] = (bf16)Wxh[t];
    Whbf[t] = (bf16)Whh[t];
    if (t < 2 * G4_) bsum[t] = bxh[t] + bhh[t];
}

// One wavefront step. blockIdx: [0,64) -> layer0 step k; [64,128) -> layer1 step k-1.
// Per WG: batch tile of 32 (bt) x 16 h-cols (hc). Wave w computes gate block w (i,f,g,o).
__global__ __launch_bounds__(256) void step_kernel(
    int k, const float* __restrict__ x,
    const bf16* __restrict__ Wxbf, const bf16* __restrict__ Whbf,
    const float* __restrict__ bsum,
    float* __restrict__ c0, float* __restrict__ c1,
    bf16* __restrict__ h0ring, bf16* __restrict__ h1ring) {
    int layer = blockIdx.x >> 6;
    int lwg   = blockIdx.x & 63;
    if (layer == 0 && k >= T_) return;   // last kernel: layer1 only
    if (layer == 1 && k == 0)  return;   // first kernel: layer0 only
    int step = layer ? (k - 1) : k;

    int bt = lwg >> 4;          // 0..3  (32 batch rows each)
    int hc = lwg & 15;          // 0..15 (16 h-cols each)
    int b0 = bt * 32;

    const bf16*  Wx   = Wxbf + (size_t)layer * G4_ * H_;
    const bf16*  Wh   = Whbf + (size_t)layer * G4_ * H_;
    const float* bs   = bsum + layer * G4_;
    float*       cbuf = layer ? c1 : c0;
    bf16*        ring = layer ? h1ring : h0ring;
    const bf16*  hin  = ring + ((size_t)((step - 1) & 1)) * BH_;
    bf16*        hout = ring + ((size_t)(step & 1)) * BH_;
    const bf16*  inbf = h0ring + ((size_t)(step & 1)) * BH_;  // layer1 input = h0(step)

    int tid  = threadIdx.x;
    int wave = tid >> 6;        // gate block: 0=i 1=f 2=g 3=o
    int lane = tid & 63;
    int nm   = lane & 15;
    int quad = lane >> 4;

    __shared__ float gl[4][32][17];   // +1 pad: conflict-free epilogue stores

    f32x4 acc0 = {0.f, 0.f, 0.f, 0.f};
    f32x4 acc1 = {0.f, 0.f, 0.f, 0.f};

    // B-frag: lane(n=nm, quad) holds W[gate_col = wrow][k = quad*8 + j] (8 contiguous k)
    int wrow = wave * 256 + hc * 16 + nm;
    const bf16* wxp = Wx + (size_t)wrow * H_ + quad * 8;
    const bf16* whp = Wh + (size_t)wrow * H_ + quad * 8;

    int bA0 = b0 + nm;          // A-frag m-tile 0 batch row
    int bA1 = b0 + 16 + nm;     // A-frag m-tile 1 batch row
    const bf16* hp0 = hin + (size_t)bA0 * H_ + quad * 8;
    const bf16* hp1 = hin + (size_t)bA1 * H_ + quad * 8;

    if (layer == 0) {
        const float* xp0 = x + ((size_t)bA0 * T_ + step) * I_ + quad * 8;
        const float* xp1 = x + ((size_t)bA1 * T_ + step) * I_ + quad * 8;
#pragma unroll
        for (int ks = 0; ks < 8; ++ks) {
            int k0 = ks * 32;
            bf16x8 bx = *(const bf16x8*)(wxp + k0);
            bf16x8 bh = *(const bf16x8*)(whp + k0);
            f32x8 xf0 = *(const f32x8*)(xp0 + k0);
            f32x8 xf1 = *(const f32x8*)(xp1 + k0);
            bf16x8 a0, a1;
#pragma unroll
            for (int j = 0; j < 8; ++j) { a0[j] = (bf16)xf0[j]; a1[j] = (bf16)xf1[j]; }
            bf16x8 h0f = *(const bf16x8*)(hp0 + k0);
            bf16x8 h1f = *(const bf16x8*)(hp1 + k0);
            acc0 = __builtin_amdgcn_mfma_f32_16x16x32_bf16(a0,  bx, acc0, 0, 0, 0);
            acc1 = __builtin_amdgcn_mfma_f32_16x16x32_bf16(a1,  bx, acc1, 0, 0, 0);
            acc0 = __builtin_amdgcn_mfma_f32_16x16x32_bf16(h0f, bh, acc0, 0, 0, 0);
            acc1 = __builtin_amdgcn_mfma_f32_16x16x32_bf16(h1f, bh, acc1, 0, 0, 0);
        }
    } else {
        const bf16* ip0 = inbf + (size_t)bA0 * H_ + quad * 8;
        const bf16* ip1 = inbf + (size_t)bA1 * H_ + quad * 8;
#pragma unroll
        for (int ks = 0; ks < 8; ++ks) {
            int k0 = ks * 32;
            bf16x8 bx = *(const bf16x8*)(wxp + k0);
            bf16x8 bh = *(const bf16x8*)(whp + k0);
            bf16x8 a0 = *(const bf16x8*)(ip0 + k0);
            bf16x8 a1 = *(const bf16x8*)(ip1 + k0);
            bf16x8 h0f = *(const bf16x8*)(hp0 + k0);
            bf16x8 h1f = *(const bf16x8*)(hp1 + k0);
            acc0 = __builtin_amdgcn_mfma_f32_16x16x32_bf16(a0,  bx, acc0, 0, 0, 0);
            acc1 = __builtin_amdgcn_mfma_f32_16x16x32_bf16(a1,  bx, acc1, 0, 0, 0);
            acc0 = __builtin_amdgcn_mfma_f32_16x16x32_bf16(h0f, bh, acc0, 0, 0, 0);
            acc1 = __builtin_amdgcn_mfma_f32_16x16x32_bf16(h1f, bh, acc1, 0, 0, 0);
        }
    }

    // C/D layout (verified m89/m91): col = lane&15, row = quad*4 + reg
#pragma unroll
    for (int r = 0; r < 4; ++r) {
        gl[wave][quad * 4 + r][nm]      = acc0[r];
        gl[wave][16 + quad * 4 + r][nm] = acc1[r];
    }
    __syncthreads();

    // Elementwise LSTM cell update: 512 (b,c) pairs over 256 threads
#pragma unroll
    for (int p = tid; p < 512; p += 256) {
        int bl = p >> 4, cl = p & 15;
        int gcol = hc * 16 + cl;
        float iv = gl[0][bl][cl] + bs[gcol];
        float fv = gl[1][bl][cl] + bs[256 + gcol];
        float gv = gl[2][bl][cl] + bs[512 + gcol];
        float ov = gl[3][bl][cl] + bs[768 + gcol];
        size_t idx = (size_t)(b0 + bl) * H_ + gcol;
        float cn = cbuf[idx] * sigm(fv) + sigm(iv) * tanhf(gv);
        cbuf[idx] = cn;
        hout[idx] = (bf16)(sigm(ov) * tanhf(cn));
    }
}

// Backward direction = ONE step with zero h,c: gates = in @ Wx^T + bsum;
// c = sig(i)*tanh(g); h = sig(o)*tanh(c). layer0: in = x[:,T-1,:] (fp32); layer1: in = hb0 (bf16).
__global__ __launch_bounds__(256) void bwd_kernel(
    int layer, const float* __restrict__ x, const bf16* __restrict__ inbf,
    const bf16* __restrict__ Wxbf, const float* __restrict__ bs,
    bf16* __restrict__ hb_out) {
    int lwg = blockIdx.x;
    int bt = lwg >> 4, hc = lwg & 15;
    int b0 = bt * 32;
    int tid = threadIdx.x, wave = tid >> 6, lane = tid & 63;
    int nm = lane & 15, quad = lane >> 4;

    __shared__ float gl[4][32][17];
    f32x4 acc0 = {0.f, 0.f, 0.f, 0.f};
    f32x4 acc1 = {0.f, 0.f, 0.f, 0.f};

    int wrow = wave * 256 + hc * 16 + nm;
    const bf16* wxp = Wxbf + (size_t)wrow * H_ + quad * 8;
    int bA0 = b0 + nm, bA1 = b0 + 16 + nm;

    if (layer == 0) {
        const float* xp0 = x + ((size_t)bA0 * T_ + (T_ - 1)) * I_ + quad * 8;
        const float* xp1 = x + ((size_t)bA1 * T_ + (T_ - 1)) * I_ + quad * 8;
#pragma unroll
        for (int ks = 0; ks < 8; ++ks) {
            int k0 = ks * 32;
            bf16x8 bx = *(const bf16x8*)(wxp + k0);
            f32x8 xf0 = *(const f32x8*)(xp0 + k0);
            f32x8 xf1 = *(const f32x8*)(xp1 + k0);
            bf16x8 a0, a1;
#pragma unroll
            for (int j = 0; j < 8; ++j) { a0[j] = (bf16)xf0[j]; a1[j] = (bf16)xf1[j]; }
            acc0 = __builtin_amdgcn_mfma_f32_16x16x32_bf16(a0, bx, acc0, 0, 0, 0);
            acc1 = __builtin_amdgcn_mfma_f32_16x16x32_bf16(a1, bx, acc1, 0, 0, 0);
        }
    } else {
        const bf16* ip0 = inbf + (size_t)bA0 * H_ + quad * 8;
        const bf16* ip1 = inbf + (size_t)bA1 * H_ + quad * 8;
#pragma unroll
        for (int ks = 0; ks < 8; ++ks) {
            int k0 = ks * 32;
            bf16x8 bx = *(const bf16x8*)(wxp + k0);
            bf16x8 a0 = *(const bf16x8*)(ip0 + k0);
            bf16x8 a1 = *(const bf16x8*)(ip1 + k0);
            acc0 = __builtin_amdgcn_mfma_f32_16x16x32_bf16(a0, bx, acc0, 0, 0, 0);
            acc1 = __builtin_amdgcn_mfma_f32_16x16x32_bf16(a1, bx, acc1, 0, 0, 0);
        }
    }
#pragma unroll
    for (int r = 0; r < 4; ++r) {
        gl[wave][quad * 4 + r][nm]      = acc0[r];
        gl[wave][16 + quad * 4 + r][nm] = acc1[r];
    }
    __syncthreads();
#pragma unroll
    for (int p = tid; p < 512; p += 256) {
        int bl = p >> 4, cl = p & 15;
        int gcol = hc * 16 + cl;
        float iv = gl[0][bl][cl] + bs[gcol];
        float gv = gl[2][bl][cl] + bs[512 + gcol];
        float ov = gl[3][bl][cl] + bs[768 + gcol];
        float cn = sigm(iv) * tanhf(gv);
        hb_out[(size_t)(b0 + bl) * H_ + gcol] = (bf16)(sigm(ov) * tanhf(cn));
    }
}

// out[b][o] = fcb[o] + sum_j hf[b][j]*fcW[o][j] + sum_j hb[b][j]*fcW[o][256+j]
__global__ __launch_bounds__(256) void fc_kernel(
    const bf16* __restrict__ hf, const bf16* __restrict__ hb,
    const float* __restrict__ fcW, const float* __restrict__ fcb,
    float* __restrict__ out) {
    int b = blockIdx.x, o = threadIdx.x;
    __shared__ float v[512];
    v[o]       = (float)hf[(size_t)b * H_ + o];
    v[256 + o] = (float)hb[(size_t)b * H_ + o];
    __syncthreads();
    const float4* wr = (const float4*)(fcW + (size_t)o * 512);
    float sum = fcb[o];
#pragma unroll 4
    for (int j4 = 0; j4 < 128; ++j4) {
        float4 w = wr[j4];
        const float* vv = &v[j4 * 4];
        sum += w.x * vv[0] + w.y * vv[1] + w.z * vv[2] + w.w * vv[3];
    }
    out[(size_t)b * 256 + o] = sum;
}

extern "C" void kernel_launch(void* const* d_in, const int* in_sizes, int n_in,
                              void* d_out, int out_size, void* d_ws, size_t ws_size,
                              hipStream_t stream) {
    const float* x   = (const float*)d_in[0];
    const float* Wxh = (const float*)d_in[1];
    const float* Whh = (const float*)d_in[2];
    const float* bxh = (const float*)d_in[3];
    const float* bhh = (const float*)d_in[4];
    const float* fcW = (const float*)d_in[5];
    const float* fcb = (const float*)d_in[6];
    float* out = (float*)d_out;

    char* ws = (char*)d_ws;
    bf16*  Wxbf = (bf16*)ws;                      // 1,048,576 B
    bf16*  Whbf = (bf16*)(ws + 1048576);          // 1,048,576 B
    float* bsum = (float*)(ws + 2097152);         //     8,192 B
    char*  st   = ws + 2105344;
    float* c0     = (float*)st;                   // 131,072 B
    float* c1     = (float*)(st + 131072);        // 131,072 B
    bf16*  h0ring = (bf16*)(st + 262144);         // 131,072 B (2 slots)
    bf16*  h1ring = (bf16*)(st + 393216);         // 131,072 B (2 slots)
    bf16*  hb0    = (bf16*)(st + 524288);         //  65,536 B
    bf16*  hb1    = (bf16*)(st + 589824);         //  65,536 B

    // zero c-state and h rings (harness poisons ws before every launch)
    hipMemsetAsync(st, 0, 524288, stream);
    prep_kernel<<<2048, 256, 0, stream>>>(Wxh, Whh, bxh, bhh, Wxbf, Whbf, bsum);

    for (int k = 0; k <= T_; ++k)
        step_kernel<<<128, 256, 0, stream>>>(k, x, Wxbf, Whbf, bsum, c0, c1, h0ring, h1ring);

    bwd_kernel<<<64, 256, 0, stream>>>(0, x, nullptr, Wxbf, bsum, hb0);
    bwd_kernel<<<64, 256, 0, stream>>>(1, x, hb0, Wxbf + (size_t)G4_ * H_, bsum + G4_, hb1);

    // forward top-layer h at step 2047 lives in h1ring slot (2047 & 1) = 1
    fc_kernel<<<128, 256, 0, stream>>>(h1ring + BH_, hb1, fcW, fcb, out);
}

// Round 2
// 17886.118 us; speedup vs baseline: 1.2947x; 1.2947x over previous
//
#include <hip/hip_runtime.h>
#include <hip/hip_bf16.h>
#include <cstdint>
#include <cstddef>

// Bidirectional 2-layer LSTM, B=128 T=2048 I=H=O=256.
// out = FC([h_fwd_top(T-1) | h_bwd_top(one step on x[T-1], zero state)]).
// Round 2: ONE persistent kernel for the forward recurrence.
//   256 WGs = 8 batch-groups x 2 layers x 16 col-slices. Weights in VGPRs,
//   c-state in registers, h exchanged via 4-deep global ring + device-scope
//   flag protocol (agent atomics; correct under XCD non-coherence).

#define B_    128
#define T_    2048
#define H_    256
#define G4_   1024         // 4*H
#define RING  4
#define GSZ   16           // batch rows per group
#define NGRP  8

using bf16   = __bf16;
using bf16x8 = __attribute__((ext_vector_type(8))) __bf16;
using f32x4  = __attribute__((ext_vector_type(4))) float;
using f32x8  = __attribute__((ext_vector_type(8))) float;

__device__ __forceinline__ float sigm(float v) { return 1.0f / (1.0f + expf(-v)); }

// Coherent 16B load (bypasses L1 and per-XCD L2 -> reads device coherence point).
// No waitcnt here: issue many, then vmwait() once.
__device__ __forceinline__ f32x4 cload16(const bf16* p) {
    f32x4 v;
    asm volatile("global_load_dwordx4 %0, %1, off sc0 sc1" : "=v"(v) : "v"(p) : "memory");
    return v;
}
__device__ __forceinline__ void vmwait() { asm volatile("s_waitcnt vmcnt(0)" ::: "memory"); }

// Convert weights to bf16, precompute bias sums. grid 2048 x 256.
__global__ void prep_kernel(const float* __restrict__ Wxh, const float* __restrict__ Whh,
                            const float* __restrict__ bxh, const float* __restrict__ bhh,
                            bf16* __restrict__ Wxbf, bf16* __restrict__ Whbf,
                            float* __restrict__ bsum) {
    int t = blockIdx.x * 256 + threadIdx.x;
    Wxbf[t] = (bf16)Wxh[t];
    Whbf[t] = (bf16)Whh[t];
    if (t < 2 * G4_) bsum[t] = bxh[t] + bhh[t];
}

// Persistent forward kernel. grid 256 x 256 threads (1 WG/CU, all co-resident).
// WG id: l = blk>>7, s = (blk>>3)&15, g = blk&7  (g == blk%8 -> XCD-local groups
// under round-robin dispatch; perf heuristic only, correctness is scope-based).
__global__ __launch_bounds__(256, 1) void lstm_persist(
    const float* __restrict__ x, const bf16* __restrict__ Wxbf, const bf16* __restrict__ Whbf,
    const float* __restrict__ bsum, bf16* __restrict__ ring0, bf16* __restrict__ ring1,
    int* prog) {
    const int g = blockIdx.x & 7;
    const int s = (blockIdx.x >> 3) & 15;
    const int l = blockIdx.x >> 7;
    const int tid  = threadIdx.x;
    const int wave = tid >> 6, lane = tid & 63;
    const int nm = lane & 15, quad = lane >> 4;

    __shared__ float gl[4][16][17];
    __shared__ __align__(16) bf16 hAbuf[16 * 264];   // padded: 264 elems/row (2-way max)
    __shared__ __align__(16) bf16 hBbuf[16 * 264];

    // ---- persistent weight fragments in VGPRs (64 regs/lane) ----
    // wave w = gate w (i,f,g,o). B-frag (verified): lane(n=nm,quad) holds
    // W[col = w*256 + s*16 + nm][k = kt*32 + quad*8 + j].
    const bf16* Wx = Wxbf + (size_t)l * G4_ * H_;
    const bf16* Wh = Whbf + (size_t)l * G4_ * H_;
    const int wrow = wave * 256 + s * 16 + nm;
    bf16x8 wfrag[16];
#pragma unroll
    for (int kt = 0; kt < 8; ++kt) {
        wfrag[kt]     = *(const bf16x8*)(Wx + (size_t)wrow * H_ + kt * 32 + quad * 8);
        wfrag[8 + kt] = *(const bf16x8*)(Wh + (size_t)wrow * H_ + kt * 32 + quad * 8);
    }

    // epilogue assignment: thread -> (batch row bl, col cl) of the 16x16 slice
    const int bl = tid >> 4, cl = tid & 15, gcol = s * 16 + cl;
    const float* bs = bsum + l * G4_;
    const float bi = bs[gcol], bff = bs[256 + gcol], bg = bs[512 + gcol], bo = bs[768 + gcol];
    float creg = 0.0f;   // c-state never touches memory

    int* prog0 = prog + g * 16;               // layer-0 progress of my group
    int* prog1 = prog + NGRP * 16 + g * 16;   // layer-1 progress of my group
    int* myprog = (l ? prog1 : prog0) + s;

    bf16* outring = l ? ring1 : ring0;

    for (int t = 0; t < T_; ++t) {
        const int sp = (t + RING - 1) & (RING - 1);   // slot of h(t-1)
        const int sc = t & (RING - 1);                // slot of h(t)

        // x prefetch for layer 0 (normal cached loads; issued before the spin)
        f32x8 xv[8];
        if (l == 0) {
            const float* xp = x + ((size_t)(g * GSZ + nm) * T_ + t) * H_ + quad * 8;
#pragma unroll
            for (int kt = 0; kt < 8; ++kt) xv[kt] = *(const f32x8*)(xp + kt * 32);
        }

        // ---- spin (wave 0 only; relaxed agent loads bypass stale L2) ----
        // layer0 step t : peers prog0 >= t (h0(t-1)), prog1 >= t-(RING-1) (slot reuse)
        // layer1 step t : prog0 >= t+1 (h0(t)),      peers prog1 >= t
        if (wave == 0) {
            const bool act = lane < 16;
            const int myi = lane & 15;
            const int need0 = l ? t + 1 : t;
            const int need1 = l ? t     : t - (RING - 1);
            while (true) {
                int v0 = act ? __hip_atomic_load(&prog0[myi], __ATOMIC_RELAXED, __HIP_MEMORY_SCOPE_AGENT) : 0x7fffffff;
                int v1 = act ? __hip_atomic_load(&prog1[myi], __ATOMIC_RELAXED, __HIP_MEMORY_SCOPE_AGENT) : 0x7fffffff;
                if (__ballot(v0 >= need0 && v1 >= need1) == ~0ull) break;
                __builtin_amdgcn_s_sleep(1);
            }
        }
        __syncthreads();

        // ---- cooperative coherent load h -> LDS (shared A-operand for all 4 waves)
        {
            const bf16* srcA = l ? (ring0 + ((size_t)sc * NGRP + g) * (GSZ * H_))   // h0(t)
                                 : (ring0 + ((size_t)sp * NGRP + g) * (GSZ * H_));  // h0(t-1)
            const int c0 = tid, c1 = tid + 256;
            const int r0 = c0 >> 5, o0 = (c0 & 31) * 8;
            const int r1 = c1 >> 5, o1 = (c1 & 31) * 8;
            f32x4 a0 = cload16(srcA + r0 * H_ + o0);
            f32x4 a1 = cload16(srcA + r1 * H_ + o1);
            f32x4 b0v = {0, 0, 0, 0}, b1v = {0, 0, 0, 0};
            if (l) {
                const bf16* srcB = ring1 + ((size_t)sp * NGRP + g) * (GSZ * H_);    // h1(t-1)
                b0v = cload16(srcB + r0 * H_ + o0);
                b1v = cload16(srcB + r1 * H_ + o1);
            }
            vmwait();
            *(f32x4*)&hAbuf[r0 * 264 + o0] = a0;
            *(f32x4*)&hAbuf[r1 * 264 + o1] = a1;
            if (l) {
                *(f32x4*)&hBbuf[r0 * 264 + o0] = b0v;
                *(f32x4*)&hBbuf[r1 * 264 + o1] = b1v;
            }
        }
        __syncthreads();

        // ---- gate GEMM: m=16(batch) n=16(gate cols) k=512, B-frags from VGPRs
        f32x4 ac0 = {0, 0, 0, 0}, ac1 = {0, 0, 0, 0};
        if (l == 0) {
#pragma unroll
            for (int kt = 0; kt < 8; ++kt) {           // k 0..255: x(t)
                bf16x8 a;
#pragma unroll
                for (int j = 0; j < 8; ++j) a[j] = (bf16)xv[kt][j];
                if (kt & 1) ac1 = __builtin_amdgcn_mfma_f32_16x16x32_bf16(a, wfrag[kt], ac1, 0, 0, 0);
                else        ac0 = __builtin_amdgcn_mfma_f32_16x16x32_bf16(a, wfrag[kt], ac0, 0, 0, 0);
            }
#pragma unroll
            for (int kt = 0; kt < 8; ++kt) {           // k 256..511: h0(t-1)
                bf16x8 a = *(const bf16x8*)&hAbuf[nm * 264 + kt * 32 + quad * 8];
                if (kt & 1) ac1 = __builtin_amdgcn_mfma_f32_16x16x32_bf16(a, wfrag[8 + kt], ac1, 0, 0, 0);
                else        ac0 = __builtin_amdgcn_mfma_f32_16x16x32_bf16(a, wfrag[8 + kt], ac0, 0, 0, 0);
            }
        } else {
#pragma unroll
            for (int kt = 0; kt < 8; ++kt) {           // k 0..255: h0(t)
                bf16x8 a = *(const bf16x8*)&hAbuf[nm * 264 + kt * 32 + quad * 8];
                if (kt & 1) ac1 = __builtin_amdgcn_mfma_f32_16x16x32_bf16(a, wfrag[kt], ac1, 0, 0, 0);
                else        ac0 = __builtin_amdgcn_mfma_f32_16x16x32_bf16(a, wfrag[kt], ac0, 0, 0, 0);
            }
#pragma unroll
            for (int kt = 0; kt < 8; ++kt) {           // k 256..511: h1(t-1)
                bf16x8 a = *(const bf16x8*)&hBbuf[nm * 264 + kt * 32 + quad * 8];
                if (kt & 1) ac1 = __builtin_amdgcn_mfma_f32_16x16x32_bf16(a, wfrag[8 + kt], ac1, 0, 0, 0);
                else        ac0 = __builtin_amdgcn_mfma_f32_16x16x32_bf16(a, wfrag[8 + kt], ac0, 0, 0, 0);
            }
        }
        f32x4 acc = ac0 + ac1;

        // C/D layout (verified): col = lane&15, row = quad*4 + r
#pragma unroll
        for (int r = 0; r < 4; ++r) gl[wave][quad * 4 + r][nm] = acc[r];
        __syncthreads();

        // ---- elementwise cell update, h store to ring ----
        {
            float iv = gl[0][bl][cl] + bi;
            float fv = gl[1][bl][cl] + bff;
            float gv = gl[2][bl][cl] + bg;
            float ov = gl[3][bl][cl] + bo;
            float cn = creg * sigm(fv) + sigm(iv) * tanhf(gv);
            creg = cn;
            float hn = sigm(ov) * tanhf(cn);
            outring[((size_t)sc * NGRP + g) * (GSZ * H_) + (size_t)bl * H_ + gcol] = (bf16)hn;
        }
        __syncthreads();   // drains vmem stores (compiler emits vmcnt(0) before s_barrier)
        if (tid == 0)
            __hip_atomic_store(myprog, t + 1, __ATOMIC_RELEASE, __HIP_MEMORY_SCOPE_AGENT);
    }
}

// Backward direction = ONE step with zero h,c per layer.
__global__ __launch_bounds__(256) void bwd_kernel(
    int layer, const float* __restrict__ x, const bf16* __restrict__ inbf,
    const bf16* __restrict__ Wxbf, const float* __restrict__ bs,
    bf16* __restrict__ hb_out) {
    int lwg = blockIdx.x;
    int bt = lwg >> 4, hc = lwg & 15;
    int b0 = bt * 32;
    int tid = threadIdx.x, wave = tid >> 6, lane = tid & 63;
    int nm = lane & 15, quad = lane >> 4;

    __shared__ float gl[4][32][17];
    f32x4 acc0 = {0.f, 0.f, 0.f, 0.f};
    f32x4 acc1 = {0.f, 0.f, 0.f, 0.f};

    int wrow = wave * 256 + hc * 16 + nm;
    const bf16* wxp = Wxbf + (size_t)wrow * H_ + quad * 8;
    int bA0 = b0 + nm, bA1 = b0 + 16 + nm;

    if (layer == 0) {
        const float* xp0 = x + ((size_t)bA0 * T_ + (T_ - 1)) * H_ + quad * 8;
        const float* xp1 = x + ((size_t)bA1 * T_ + (T_ - 1)) * H_ + quad * 8;
#pragma unroll
        for (int ks = 0; ks < 8; ++ks) {
            int k0 = ks * 32;
            bf16x8 bx = *(const bf16x8*)(wxp + k0);
            f32x8 xf0 = *(const f32x8*)(xp0 + k0);
            f32x8 xf1 = *(const f32x8*)(xp1 + k0);
            bf16x8 a0, a1;
#pragma unroll
            for (int j = 0; j < 8; ++j) { a0[j] = (bf16)xf0[j]; a1[j] = (bf16)xf1[j]; }
            acc0 = __builtin_amdgcn_mfma_f32_16x16x32_bf16(a0, bx, acc0, 0, 0, 0);
            acc1 = __builtin_amdgcn_mfma_f32_16x16x32_bf16(a1, bx, acc1, 0, 0, 0);
        }
    } else {
        const bf16* ip0 = inbf + (size_t)bA0 * H_ + quad * 8;
        const bf16* ip1 = inbf + (size_t)bA1 * H_ + quad * 8;
#pragma unroll
        for (int ks = 0; ks < 8; ++ks) {
            int k0 = ks * 32;
            bf16x8 bx = *(const bf16x8*)(wxp + k0);
            bf16x8 a0 = *(const bf16x8*)(ip0 + k0);
            bf16x8 a1 = *(const bf16x8*)(ip1 + k0);
            acc0 = __builtin_amdgcn_mfma_f32_16x16x32_bf16(a0, bx, acc0, 0, 0, 0);
            acc1 = __builtin_amdgcn_mfma_f32_16x16x32_bf16(a1, bx, acc1, 0, 0, 0);
        }
    }
#pragma unroll
    for (int r = 0; r < 4; ++r) {
        gl[wave][quad * 4 + r][nm]      = acc0[r];
        gl[wave][16 + quad * 4 + r][nm] = acc1[r];
    }
    __syncthreads();
#pragma unroll
    for (int p = tid; p < 512; p += 256) {
        int bl = p >> 4, cl = p & 15;
        int gcol = hc * 16 + cl;
        float iv = gl[0][bl][cl] + bs[gcol];
        float gv = gl[2][bl][cl] + bs[512 + gcol];
        float ov = gl[3][bl][cl] + bs[768 + gcol];
        float cn = sigm(iv) * tanhf(gv);
        hb_out[(size_t)(b0 + bl) * H_ + gcol] = (bf16)(sigm(ov) * tanhf(cn));
    }
}

// out[b][o] = fcb[o] + hf[b] . fcW[o][0:256] + hb[b] . fcW[o][256:512]
__global__ __launch_bounds__(256) void fc_kernel(
    const bf16* __restrict__ hf, const bf16* __restrict__ hb,
    const float* __restrict__ fcW, const float* __restrict__ fcb,
    float* __restrict__ out) {
    int b = blockIdx.x, o = threadIdx.x;
    __shared__ float v[512];
    v[o]       = (float)hf[(size_t)b * H_ + o];
    v[256 + o] = (float)hb[(size_t)b * H_ + o];
    __syncthreads();
    const float4* wr = (const float4*)(fcW + (size_t)o * 512);
    float sum = fcb[o];
#pragma unroll 4
    for (int j4 = 0; j4 < 128; ++j4) {
        float4 w = wr[j4];
        const float* vv = &v[j4 * 4];
        sum += w.x * vv[0] + w.y * vv[1] + w.z * vv[2] + w.w * vv[3];
    }
    out[(size_t)b * 256 + o] = sum;
}

extern "C" void kernel_launch(void* const* d_in, const int* in_sizes, int n_in,
                              void* d_out, int out_size, void* d_ws, size_t ws_size,
                              hipStream_t stream) {
    const float* x   = (const float*)d_in[0];
    const float* Wxh = (const float*)d_in[1];
    const float* Whh = (const float*)d_in[2];
    const float* bxh = (const float*)d_in[3];
    const float* bhh = (const float*)d_in[4];
    const float* fcW = (const float*)d_in[5];
    const float* fcb = (const float*)d_in[6];
    float* out = (float*)d_out;

    char* ws = (char*)d_ws;
    bf16*  Wxbf  = (bf16*)ws;                      // 1,048,576
    bf16*  Whbf  = (bf16*)(ws + 1048576);          // 1,048,576
    float* bsum  = (float*)(ws + 2097152);         //     8,192
    bf16*  ring0 = (bf16*)(ws + 2105344);          //   262,144  (4 slots x 8 grp x 16x256)
    bf16*  ring1 = (bf16*)(ws + 2367488);          //   262,144
    int*   prog  = (int*)(ws + 2629632);           //     1,024
    bf16*  hb0   = (bf16*)(ws + 2630656);          //    65,536
    bf16*  hb1   = (bf16*)(ws + 2696192);          //    65,536

    // zero rings (h(-1)=0) + progress flags (ws is re-poisoned before every launch)
    hipMemsetAsync(ws + 2105344, 0, 262144 * 2 + 1024, stream);
    prep_kernel<<<2048, 256, 0, stream>>>(Wxh, Whh, bxh, bhh, Wxbf, Whbf, bsum);

    lstm_persist<<<256, 256, 0, stream>>>(x, Wxbf, Whbf, bsum, ring0, ring1, prog);

    bwd_kernel<<<64, 256, 0, stream>>>(0, x, nullptr, Wxbf, bsum, hb0);
    bwd_kernel<<<64, 256, 0, stream>>>(1, x, hb0, Wxbf + (size_t)G4_ * H_, bsum + G4_, hb1);

    // h_fwd_top(2047) lives in ring1 slot 2047%4 = 3
    fc_kernel<<<128, 256, 0, stream>>>(ring1 + (size_t)3 * NGRP * GSZ * H_, hb1, fcW, fcb, out);
}

// Round 3
// 7976.091 us; speedup vs baseline: 2.9034x; 2.2425x over previous
//
#include <hip/hip_runtime.h>
#include <hip/hip_bf16.h>
#include <cstdint>
#include <cstddef>

// Bidirectional 2-layer LSTM, B=128 T=2048 I=H=O=256.
// out = FC([h_fwd_top(T-1) | h_bwd_top(one step on x[T-1], zero state)]).
// Round 3: persistent kernel, but ALL inter-WG traffic uses explicit sc0 sc1
// write-through/bypass ops (no atomic builtins -> no buffer_wbl2 / buffer_inv
// cache maintenance, which dominated round 2 at ~8.7us/step).

#define B_    128
#define T_    2048
#define H_    256
#define G4_   1024         // 4*H
#define RING  4
#define GSZ   16           // batch rows per group
#define NGRP  8

using bf16   = __bf16;
using bf16x8 = __attribute__((ext_vector_type(8))) __bf16;
using f32x4  = __attribute__((ext_vector_type(4))) float;
using f32x8  = __attribute__((ext_vector_type(8))) float;

__device__ __forceinline__ float sigm(float v) { return 1.0f / (1.0f + expf(-v)); }
// fast device versions for the hot loop
__device__ __forceinline__ float fsigm(float v) { return 1.0f / (1.0f + __expf(-v)); }
__device__ __forceinline__ float ftanh(float v) { return 1.0f - 2.0f / (__expf(2.0f * v) + 1.0f); }

// ---- device-coherent (bypass L1+L2) memory ops; no cache maintenance ----
__device__ __forceinline__ f32x4 cload16(const bf16* p) {
    f32x4 v;
    asm volatile("global_load_dwordx4 %0, %1, off sc0 sc1" : "=v"(v) : "v"(p) : "memory");
    return v;
}
__device__ __forceinline__ void vmwait() { asm volatile("s_waitcnt vmcnt(0)" ::: "memory"); }
__device__ __forceinline__ int cload_int(const int* p) {
    int v;
    asm volatile("global_load_dword %0, %1, off sc0 sc1" : "=v"(v) : "v"(p) : "memory");
    asm volatile("s_waitcnt vmcnt(0)" ::: "memory");
    return v;
}
__device__ __forceinline__ void cstore_bf16(bf16* p, float hval) {
    bf16 hv = (bf16)hval;
    int iv = (int)__builtin_bit_cast(unsigned short, hv);
    asm volatile("global_store_short %0, %1, off sc0 sc1" :: "v"(p), "v"(iv) : "memory");
}
__device__ __forceinline__ void cstore_int(int* p, int v) {
    asm volatile("global_store_dword %0, %1, off sc0 sc1" :: "v"(p), "v"(v) : "memory");
}

// Convert weights to bf16, precompute bias sums. grid 2048 x 256.
__global__ void prep_kernel(const float* __restrict__ Wxh, const float* __restrict__ Whh,
                            const float* __restrict__ bxh, const float* __restrict__ bhh,
                            bf16* __restrict__ Wxbf, bf16* __restrict__ Whbf,
                            float* __restrict__ bsum) {
    int t = blockIdx.x * 256 + threadIdx.x;
    Wxbf[t] = (bf16)Wxh[t];
    Whbf[t] = (bf16)Whh[t];
    if (t < 2 * G4_) bsum[t] = bxh[t] + bhh[t];
}

// Persistent forward kernel. grid 256 x 256 threads (1 WG/CU, co-resident).
// WG id: l = blk>>7, s = (blk>>3)&15, g = blk&7.
__global__ __launch_bounds__(256, 1) void lstm_persist(
    const float* __restrict__ x, const bf16* __restrict__ Wxbf, const bf16* __restrict__ Whbf,
    const float* __restrict__ bsum, bf16* __restrict__ ring0, bf16* __restrict__ ring1,
    int* prog) {
    const int g = blockIdx.x & 7;
    const int s = (blockIdx.x >> 3) & 15;
    const int l = blockIdx.x >> 7;
    const int tid  = threadIdx.x;
    const int wave = tid >> 6, lane = tid & 63;
    const int nm = lane & 15, quad = lane >> 4;

    __shared__ float gl[4][16][17];
    __shared__ __align__(16) bf16 hAbuf[16 * 264];
    __shared__ __align__(16) bf16 hBbuf[16 * 264];

    // persistent weight B-fragments in VGPRs (wave w = gate w)
    const bf16* Wx = Wxbf + (size_t)l * G4_ * H_;
    const bf16* Wh = Whbf + (size_t)l * G4_ * H_;
    const int wrow = wave * 256 + s * 16 + nm;
    bf16x8 wfrag[16];
#pragma unroll
    for (int kt = 0; kt < 8; ++kt) {
        wfrag[kt]     = *(const bf16x8*)(Wx + (size_t)wrow * H_ + kt * 32 + quad * 8);
        wfrag[8 + kt] = *(const bf16x8*)(Wh + (size_t)wrow * H_ + kt * 32 + quad * 8);
    }

    const int bl = tid >> 4, cl = tid & 15, gcol = s * 16 + cl;
    const float* bs = bsum + l * G4_;
    const float bi = bs[gcol], bff = bs[256 + gcol], bg = bs[512 + gcol], bo = bs[768 + gcol];
    float creg = 0.0f;

    int* prog0 = prog + g * 32;        // [16] layer-0 slice flags of my group
    int* prog1 = prog0 + 16;           // [16] layer-1 slice flags
    int* myprog = (l ? prog1 : prog0) + s;
    bf16* outring = l ? ring1 : ring0;

    // spin assignment (wave 0, lanes 0..31): lane<16 -> prog0[lane], else prog1[lane-16]
    int* spin_p = (lane < 16) ? (prog0 + lane) : (prog1 + (lane & 15));

    for (int t = 0; t < T_; ++t) {
        const int sp = (t + RING - 1) & (RING - 1);   // slot of h(t-1)
        const int sc = t & (RING - 1);                // slot of h(t)

        // x prefetch for layer 0 (plain cached loads, issued before the spin)
        f32x8 xv[8];
        if (l == 0) {
            const float* xp = x + ((size_t)(g * GSZ + nm) * T_ + t) * H_ + quad * 8;
#pragma unroll
            for (int kt = 0; kt < 8; ++kt) xv[kt] = *(const f32x8*)(xp + kt * 32);
        }

        // ---- spin: pure sc0 sc1 loads, no cache maintenance ----
        // L0 step t: prog0 >= t (peers wrote h0(t-1)), prog1 >= t-(RING-1) (slot free)
        // L1 step t: prog0 >= t+1 (h0(t) ready),       prog1 >= t (peers wrote h1(t-1))
        if (wave == 0 && lane < 32) {
            const int need = (lane < 16) ? (l ? t + 1 : t)
                                         : (l ? t     : t - (RING - 1));
            while (cload_int(spin_p) < need) {}
        }
        __syncthreads();

        // ---- cooperative coherent load h -> LDS ----
        {
            const bf16* srcA = l ? (ring0 + ((size_t)sc * NGRP + g) * (GSZ * H_))   // h0(t)
                                 : (ring0 + ((size_t)sp * NGRP + g) * (GSZ * H_));  // h0(t-1)
            const int c0 = tid, c1 = tid + 256;
            const int r0 = c0 >> 5, o0 = (c0 & 31) * 8;
            const int r1 = c1 >> 5, o1 = (c1 & 31) * 8;
            f32x4 a0 = cload16(srcA + r0 * H_ + o0);
            f32x4 a1 = cload16(srcA + r1 * H_ + o1);
            f32x4 b0v = {0, 0, 0, 0}, b1v = {0, 0, 0, 0};
            if (l) {
                const bf16* srcB = ring1 + ((size_t)sp * NGRP + g) * (GSZ * H_);    // h1(t-1)
                b0v = cload16(srcB + r0 * H_ + o0);
                b1v = cload16(srcB + r1 * H_ + o1);
            }
            vmwait();
            *(f32x4*)&hAbuf[r0 * 264 + o0] = a0;
            *(f32x4*)&hAbuf[r1 * 264 + o1] = a1;
            if (l) {
                *(f32x4*)&hBbuf[r0 * 264 + o0] = b0v;
                *(f32x4*)&hBbuf[r1 * 264 + o1] = b1v;
            }
        }
        __syncthreads();

        // ---- gate GEMM: m=16 n=16 k=512, B-frags resident in VGPRs ----
        f32x4 ac0 = {0, 0, 0, 0}, ac1 = {0, 0, 0, 0};
        if (l == 0) {
#pragma unroll
            for (int kt = 0; kt < 8; ++kt) {           // k 0..255: x(t)
                bf16x8 a;
#pragma unroll
                for (int j = 0; j < 8; ++j) a[j] = (bf16)xv[kt][j];
                if (kt & 1) ac1 = __builtin_amdgcn_mfma_f32_16x16x32_bf16(a, wfrag[kt], ac1, 0, 0, 0);
                else        ac0 = __builtin_amdgcn_mfma_f32_16x16x32_bf16(a, wfrag[kt], ac0, 0, 0, 0);
            }
#pragma unroll
            for (int kt = 0; kt < 8; ++kt) {           // k 256..511: h0(t-1)
                bf16x8 a = *(const bf16x8*)&hAbuf[nm * 264 + kt * 32 + quad * 8];
                if (kt & 1) ac1 = __builtin_amdgcn_mfma_f32_16x16x32_bf16(a, wfrag[8 + kt], ac1, 0, 0, 0);
                else        ac0 = __builtin_amdgcn_mfma_f32_16x16x32_bf16(a, wfrag[8 + kt], ac0, 0, 0, 0);
            }
        } else {
#pragma unroll
            for (int kt = 0; kt < 8; ++kt) {           // k 0..255: h0(t)
                bf16x8 a = *(const bf16x8*)&hAbuf[nm * 264 + kt * 32 + quad * 8];
                if (kt & 1) ac1 = __builtin_amdgcn_mfma_f32_16x16x32_bf16(a, wfrag[kt], ac1, 0, 0, 0);
                else        ac0 = __builtin_amdgcn_mfma_f32_16x16x32_bf16(a, wfrag[kt], ac0, 0, 0, 0);
            }
#pragma unroll
            for (int kt = 0; kt < 8; ++kt) {           // k 256..511: h1(t-1)
                bf16x8 a = *(const bf16x8*)&hBbuf[nm * 264 + kt * 32 + quad * 8];
                if (kt & 1) ac1 = __builtin_amdgcn_mfma_f32_16x16x32_bf16(a, wfrag[8 + kt], ac1, 0, 0, 0);
                else        ac0 = __builtin_amdgcn_mfma_f32_16x16x32_bf16(a, wfrag[8 + kt], ac0, 0, 0, 0);
            }
        }
        f32x4 acc = ac0 + ac1;

        // C/D layout (verified): col = lane&15, row = quad*4 + r
#pragma unroll
        for (int r = 0; r < 4; ++r) gl[wave][quad * 4 + r][nm] = acc[r];
        __syncthreads();

        // ---- elementwise cell update; h write-through to ring ----
        {
            float iv = gl[0][bl][cl] + bi;
            float fv = gl[1][bl][cl] + bff;
            float gv = gl[2][bl][cl] + bg;
            float ov = gl[3][bl][cl] + bo;
            float cn = creg * fsigm(fv) + fsigm(iv) * ftanh(gv);
            creg = cn;
            float hn = fsigm(ov) * ftanh(cn);
            cstore_bf16(outring + ((size_t)sc * NGRP + g) * (GSZ * H_) + (size_t)bl * H_ + gcol, hn);
        }
        vmwait();            // own h store drained to coherence point
        __syncthreads();     // all threads' stores drained
        if (tid == 0) cstore_int(myprog, t + 1);   // release: plain sc1 flag store
    }
}

// Backward direction = ONE step with zero h,c per layer.
__global__ __launch_bounds__(256) void bwd_kernel(
    int layer, const float* __restrict__ x, const bf16* __restrict__ inbf,
    const bf16* __restrict__ Wxbf, const float* __restrict__ bs,
    bf16* __restrict__ hb_out) {
    int lwg = blockIdx.x;
    int bt = lwg >> 4, hc = lwg & 15;
    int b0 = bt * 32;
    int tid = threadIdx.x, wave = tid >> 6, lane = tid & 63;
    int nm = lane & 15, quad = lane >> 4;

    __shared__ float gl[4][32][17];
    f32x4 acc0 = {0.f, 0.f, 0.f, 0.f};
    f32x4 acc1 = {0.f, 0.f, 0.f, 0.f};

    int wrow = wave * 256 + hc * 16 + nm;
    const bf16* wxp = Wxbf + (size_t)wrow * H_ + quad * 8;
    int bA0 = b0 + nm, bA1 = b0 + 16 + nm;

    if (layer == 0) {
        const float* xp0 = x + ((size_t)bA0 * T_ + (T_ - 1)) * H_ + quad * 8;
        const float* xp1 = x + ((size_t)bA1 * T_ + (T_ - 1)) * H_ + quad * 8;
#pragma unroll
        for (int ks = 0; ks < 8; ++ks) {
            int k0 = ks * 32;
            bf16x8 bx = *(const bf16x8*)(wxp + k0);
            f32x8 xf0 = *(const f32x8*)(xp0 + k0);
            f32x8 xf1 = *(const f32x8*)(xp1 + k0);
            bf16x8 a0, a1;
#pragma unroll
            for (int j = 0; j < 8; ++j) { a0[j] = (bf16)xf0[j]; a1[j] = (bf16)xf1[j]; }
            acc0 = __builtin_amdgcn_mfma_f32_16x16x32_bf16(a0, bx, acc0, 0, 0, 0);
            acc1 = __builtin_amdgcn_mfma_f32_16x16x32_bf16(a1, bx, acc1, 0, 0, 0);
        }
    } else {
        const bf16* ip0 = inbf + (size_t)bA0 * H_ + quad * 8;
        const bf16* ip1 = inbf + (size_t)bA1 * H_ + quad * 8;
#pragma unroll
        for (int ks = 0; ks < 8; ++ks) {
            int k0 = ks * 32;
            bf16x8 bx = *(const bf16x8*)(wxp + k0);
            bf16x8 a0 = *(const bf16x8*)(ip0 + k0);
            bf16x8 a1 = *(const bf16x8*)(ip1 + k0);
            acc0 = __builtin_amdgcn_mfma_f32_16x16x32_bf16(a0, bx, acc0, 0, 0, 0);
            acc1 = __builtin_amdgcn_mfma_f32_16x16x32_bf16(a1, bx, acc1, 0, 0, 0);
        }
    }
#pragma unroll
    for (int r = 0; r < 4; ++r) {
        gl[wave][quad * 4 + r][nm]      = acc0[r];
        gl[wave][16 + quad * 4 + r][nm] = acc1[r];
    }
    __syncthreads();
#pragma unroll
    for (int p = tid; p < 512; p += 256) {
        int bl = p >> 4, cl = p & 15;
        int gcol = hc * 16 + cl;
        float iv = gl[0][bl][cl] + bs[gcol];
        float gv = gl[2][bl][cl] + bs[512 + gcol];
        float ov = gl[3][bl][cl] + bs[768 + gcol];
        float cn = sigm(iv) * tanhf(gv);
        hb_out[(size_t)(b0 + bl) * H_ + gcol] = (bf16)(sigm(ov) * tanhf(cn));
    }
}

// out[b][o] = fcb[o] + hf[b] . fcW[o][0:256] + hb[b] . fcW[o][256:512]
__global__ __launch_bounds__(256) void fc_kernel(
    const bf16* __restrict__ hf, const bf16* __restrict__ hb,
    const float* __restrict__ fcW, const float* __restrict__ fcb,
    float* __restrict__ out) {
    int b = blockIdx.x, o = threadIdx.x;
    __shared__ float v[512];
    v[o]       = (float)hf[(size_t)b * H_ + o];
    v[256 + o] = (float)hb[(size_t)b * H_ + o];
    __syncthreads();
    const float4* wr = (const float4*)(fcW + (size_t)o * 512);
    float sum = fcb[o];
#pragma unroll 4
    for (int j4 = 0; j4 < 128; ++j4) {
        float4 w = wr[j4];
        const float* vv = &v[j4 * 4];
        sum += w.x * vv[0] + w.y * vv[1] + w.z * vv[2] + w.w * vv[3];
    }
    out[(size_t)b * 256 + o] = sum;
}

extern "C" void kernel_launch(void* const* d_in, const int* in_sizes, int n_in,
                              void* d_out, int out_size, void* d_ws, size_t ws_size,
                              hipStream_t stream) {
    const float* x   = (const float*)d_in[0];
    const float* Wxh = (const float*)d_in[1];
    const float* Whh = (const float*)d_in[2];
    const float* bxh = (const float*)d_in[3];
    const float* bhh = (const float*)d_in[4];
    const float* fcW = (const float*)d_in[5];
    const float* fcb = (const float*)d_in[6];
    float* out = (float*)d_out;

    char* ws = (char*)d_ws;
    bf16*  Wxbf  = (bf16*)ws;                      // 1,048,576
    bf16*  Whbf  = (bf16*)(ws + 1048576);          // 1,048,576
    float* bsum  = (float*)(ws + 2097152);         //     8,192
    bf16*  ring0 = (bf16*)(ws + 2105344);          //   262,144  (4 slots x 8 grp x 16x256)
    bf16*  ring1 = (bf16*)(ws + 2367488);          //   262,144
    int*   prog  = (int*)(ws + 2629632);           //     1,024  (8 grp x 32)
    bf16*  hb0   = (bf16*)(ws + 2630656);          //    65,536
    bf16*  hb1   = (bf16*)(ws + 2696192);          //    65,536

    hipMemsetAsync(ws + 2105344, 0, 262144 * 2 + 1024, stream);
    prep_kernel<<<2048, 256, 0, stream>>>(Wxh, Whh, bxh, bhh, Wxbf, Whbf, bsum);

    lstm_persist<<<256, 256, 0, stream>>>(x, Wxbf, Whbf, bsum, ring0, ring1, prog);

    bwd_kernel<<<64, 256, 0, stream>>>(0, x, nullptr, Wxbf, bsum, hb0);
    bwd_kernel<<<64, 256, 0, stream>>>(1, x, hb0, Wxbf + (size_t)G4_ * H_, bsum + G4_, hb1);

    // h_fwd_top(2047) lives in ring1 slot 2047%4 = 3
    fc_kernel<<<128, 256, 0, stream>>>(ring1 + (size_t)3 * NGRP * GSZ * H_, hb1, fcW, fcb, out);
}

// Round 4
// 5661.478 us; speedup vs baseline: 4.0905x; 1.4088x over previous
//
#include <hip/hip_runtime.h>
#include <hip/hip_bf16.h>
#include <cstdint>
#include <cstddef>

// Bidirectional 2-layer LSTM, B=128 T=2048 I=H=O=256.
// out = FC([h_fwd_top(T-1) | h_bwd_top(one step on x[T-1], zero state)]).
// Round 4: persistent kernel with SINGLE-HOP tagged-chunk handshake:
//   h slices published as 16B chunks = 7 bf16 payload + 16-bit epoch tag
//   (atomic 16B stores/loads via dwordx4 sc0 sc1). Consumers poll the data
//   directly -- no flag hop, no store drain, no post-detect reload.
//   x prefetched one step ahead via global_load_lds double-buffer.
//   Backpressure: prog flags checked every 4th step (RING=8).

#define B_    128
#define T_    2048
#define H_    256
#define G4_   1024
#define RING  8
#define GSZ   16
#define NGRP  8
#define SLICE_BYTES 640         // 37 chunks x 16B, padded to 40
#define GRP_BYTES   (16 * SLICE_BYTES)          // 10240
#define SLOT_BYTES  (NGRP * GRP_BYTES)          // 81920

using bf16   = __bf16;
using bf16x8 = __attribute__((ext_vector_type(8))) __bf16;
using f32x4  = __attribute__((ext_vector_type(4))) float;
using f32x8  = __attribute__((ext_vector_type(8))) float;
using u32x4  = __attribute__((ext_vector_type(4))) unsigned int;

__device__ __forceinline__ float sigm(float v) { return 1.0f / (1.0f + expf(-v)); }
__device__ __forceinline__ float fsigm(float v) { return 1.0f / (1.0f + __expf(-v)); }
__device__ __forceinline__ float ftanh(float v) { return 1.0f - 2.0f / (__expf(2.0f * v) + 1.0f); }

// device-coherent (bypass L1+L2) ops
__device__ __forceinline__ u32x4 cload16u(const void* p) {
    u32x4 v;
    asm volatile("global_load_dwordx4 %0, %1, off sc0 sc1" : "=v"(v) : "v"(p) : "memory");
    return v;
}
__device__ __forceinline__ void cstore16(void* p, u32x4 v) {
    asm volatile("global_store_dwordx4 %0, %1, off sc0 sc1" :: "v"(p), "v"(v) : "memory");
}
__device__ __forceinline__ void vmwait() { asm volatile("s_waitcnt vmcnt(0)" ::: "memory"); }
__device__ __forceinline__ int cload_int(const int* p) {
    int v;
    asm volatile("global_load_dword %0, %1, off sc0 sc1" : "=v"(v) : "v"(p) : "memory");
    asm volatile("s_waitcnt vmcnt(0)" ::: "memory");
    return v;
}
__device__ __forceinline__ void cstore_int(int* p, int v) {
    asm volatile("global_store_dword %0, %1, off sc0 sc1" :: "v"(p), "v"(v) : "memory");
}

#define GLDS16(gp, lp) __builtin_amdgcn_global_load_lds( \
    (const __attribute__((address_space(1))) void*)(gp), \
    (__attribute__((address_space(3))) void*)(lp), 16, 0, 0)

__global__ void prep_kernel(const float* __restrict__ Wxh, const float* __restrict__ Whh,
                            const float* __restrict__ bxh, const float* __restrict__ bhh,
                            bf16* __restrict__ Wxbf, bf16* __restrict__ Whbf,
                            float* __restrict__ bsum) {
    int t = blockIdx.x * 256 + threadIdx.x;
    Wxbf[t] = (bf16)Wxh[t];
    Whbf[t] = (bf16)Whh[t];
    if (t < 2 * G4_) bsum[t] = bxh[t] + bhh[t];
}

// Persistent forward kernel. 256 WGs = (layer l, slice ms, group g).
__global__ __launch_bounds__(256, 1) void lstm_persist(
    const float* __restrict__ x, const bf16* __restrict__ Wxbf, const bf16* __restrict__ Whbf,
    const float* __restrict__ bsum, char* __restrict__ ring0c, char* __restrict__ ring1c,
    int* prog, bf16* __restrict__ hf_out) {
    const int g  = blockIdx.x & 7;
    const int ms = (blockIdx.x >> 3) & 15;   // my 16-col slice
    const int l  = blockIdx.x >> 7;
    const int tid  = threadIdx.x;
    const int wave = tid >> 6, lane = tid & 63;
    const int nm = lane & 15, quad = lane >> 4;

    __shared__ float          xs[2][16 * 260];      // x double-buffer (f32, +4 pad)
    __shared__ unsigned short hAb[16 * 264];        // h A-operand (bf16 bits, +8 pad)
    __shared__ unsigned short hBb[16 * 264];
    __shared__ float          gl[4][16][17];
    __shared__ unsigned short hOutS[256];

    // persistent weight B-fragments (wave w = gate w)
    const bf16* Wx = Wxbf + (size_t)l * G4_ * H_;
    const bf16* Wh = Whbf + (size_t)l * G4_ * H_;
    const int wrow = wave * 256 + ms * 16 + nm;
    bf16x8 wfrag[16];
#pragma unroll
    for (int kt = 0; kt < 8; ++kt) {
        wfrag[kt]     = *(const bf16x8*)(Wx + (size_t)wrow * H_ + kt * 32 + quad * 8);
        wfrag[8 + kt] = *(const bf16x8*)(Wh + (size_t)wrow * H_ + kt * 32 + quad * 8);
    }

    const int bl = tid >> 4, cl = tid & 15, gcol = ms * 16 + cl;
    const float* bs = bsum + l * G4_;
    const float bi = bs[gcol], bff = bs[256 + gcol], bg = bs[512 + gcol], bo = bs[768 + gcol];
    float creg = 0.0f;

    // ---- chunk metadata (fixed for all steps) ----
    // L0 consumes hA = ring0 (15 peer slices, own slice prefilled from LDS).
    // L1 consumes hA = ring0 (all 16) + hB = ring1 (15 peers).
    unsigned maskAct = 0, maskB = 0;
    int coff[5], j7[5], ldsb[5];
#pragma unroll
    for (int i = 0; i < 5; ++i) {
        int q = tid + 256 * i;
        bool valid, isb = false;
        int qq = q;
        if (l) { valid = q < 1147; if (q >= 592) { isb = true; qq = q - 592; } }
        else   { valid = q < 555; }
        int sl = (int)(((unsigned)qq * 1772u) >> 16);   // /37 (valid to 591)
        int jj = qq - sl * 37;
        int sr = (!l || isb) ? (sl + (sl >= ms)) : sl;  // skip own slice in peer lists
        coff[i] = g * GRP_BYTES + sr * SLICE_BYTES + jj * 16;
        j7[i]   = jj * 7;
        ldsb[i] = sr * 16;
        if (valid) { maskAct |= 1u << i; if (isb) maskB |= 1u << i; }
    }

    char* outringc = l ? ring1c : ring0c;
    int*  myprog   = prog + g * 32 + l * 16 + ms;

    // x prefetch for t=0
    if (l == 0) {
        const int row = wave * 4;
#pragma unroll
        for (int r4 = 0; r4 < 4; ++r4) {
            const float* gp = x + ((size_t)(g * 16 + row + r4) * T_ + 0) * 256 + lane * 4;
            GLDS16(gp, &xs[0][(row + r4) * 260]);
        }
    }

    for (int t = 0; t < T_; ++t) {
        // ---- x prefetch for t+1 (overlaps everything below) ----
        if (l == 0 && t + 1 < T_) {
            const int row = wave * 4;
#pragma unroll
            for (int r4 = 0; r4 < 4; ++r4) {
                const float* gp = x + ((size_t)(g * 16 + row + r4) * T_ + (t + 1)) * 256 + lane * 4;
                GLDS16(gp, &xs[(t + 1) & 1][(row + r4) * 260]);
            }
        }

        // ---- single-hop tagged consume ----
        const char* pA = (l ? ring0c + ((size_t)(t & 7)) * SLOT_BYTES
                            : ring0c + ((size_t)((t - 1) & 7)) * SLOT_BYTES);
        const char* pB = ring1c + ((size_t)((t - 1) & 7)) * SLOT_BYTES;
        const unsigned tagA = l ? (unsigned)(t + 1) : (unsigned)t;
        const unsigned tagB = (unsigned)t;

        unsigned pend = maskAct;
        if (t == 0) pend &= ~maskB;          // h1(-1)=0: skip B at t=0
        if (l == 0 && t == 0) pend = 0;      // h0(-1)=0: no consume at all
        if (pend == 0) vmwait();             // still drain x prefetch (L0 t=0)

        u32x4 ch[5];
        while (pend) {
#pragma unroll
            for (int i = 0; i < 5; ++i)
                if (pend & (1u << i))
                    ch[i] = cload16u(((maskB >> i) & 1 ? pB : pA) + coff[i]);
            vmwait();
#pragma unroll
            for (int i = 0; i < 5; ++i)
                if (pend & (1u << i)) {
                    unsigned tg = ch[i][3] >> 16;
                    if (tg == (((maskB >> i) & 1) ? tagB : tagA)) {
                        unsigned short* dst = ((maskB >> i) & 1) ? hBb : hAb;
#pragma unroll
                        for (int p = 0; p < 7; ++p) {
                            int v = j7[i] + p;
                            if (v < 256) {
                                unsigned w = ch[i][p >> 1];
                                unsigned short val = (p & 1) ? (unsigned short)(w >> 16)
                                                             : (unsigned short)(w & 0xffff);
                                dst[(v >> 4) * 264 + ldsb[i] + (v & 15)] = val;
                            }
                        }
                        pend &= ~(1u << i);
                    }
                }
        }
        __syncthreads();   // b1: hA/hB/xs ready

        if (tid == 0) cstore_int(myprog, t + 1);   // consumption progress (off critical path)
        // backpressure: every 4th step ensure whole group >= t-4 (slot reuse depth 8)
        if ((t & 3) == 0 && t >= 8 && wave == 0 && lane < 32) {
            int* bp = prog + g * 32 + lane;
            while (cload_int(bp) < t - 4) {}
        }

        // ---- gate GEMM: m=16 n=16 k=512 ----
        f32x4 ac0 = {0, 0, 0, 0}, ac1 = {0, 0, 0, 0};
        if (l == 0) {
            const float* xrow = &xs[t & 1][nm * 260 + quad * 8];
#pragma unroll
            for (int kt = 0; kt < 8; ++kt) {            // k 0..255: x(t)
                f32x4 xa = *(const f32x4*)(xrow + kt * 32);
                f32x4 xb = *(const f32x4*)(xrow + kt * 32 + 4);
                bf16x8 a;
#pragma unroll
                for (int j = 0; j < 4; ++j) { a[j] = (bf16)xa[j]; a[4 + j] = (bf16)xb[j]; }
                if (kt & 1) ac1 = __builtin_amdgcn_mfma_f32_16x16x32_bf16(a, wfrag[kt], ac1, 0, 0, 0);
                else        ac0 = __builtin_amdgcn_mfma_f32_16x16x32_bf16(a, wfrag[kt], ac0, 0, 0, 0);
            }
            if (t > 0) {
#pragma unroll
                for (int kt = 0; kt < 8; ++kt) {        // k 256..511: h0(t-1)
                    bf16x8 a = *(const bf16x8*)&hAb[nm * 264 + kt * 32 + quad * 8];
                    if (kt & 1) ac1 = __builtin_amdgcn_mfma_f32_16x16x32_bf16(a, wfrag[8 + kt], ac1, 0, 0, 0);
                    else        ac0 = __builtin_amdgcn_mfma_f32_16x16x32_bf16(a, wfrag[8 + kt], ac0, 0, 0, 0);
                }
            }
        } else {
#pragma unroll
            for (int kt = 0; kt < 8; ++kt) {            // k 0..255: h0(t)
                bf16x8 a = *(const bf16x8*)&hAb[nm * 264 + kt * 32 + quad * 8];
                if (kt & 1) ac1 = __builtin_amdgcn_mfma_f32_16x16x32_bf16(a, wfrag[kt], ac1, 0, 0, 0);
                else        ac0 = __builtin_amdgcn_mfma_f32_16x16x32_bf16(a, wfrag[kt], ac0, 0, 0, 0);
            }
            if (t > 0) {
#pragma unroll
                for (int kt = 0; kt < 8; ++kt) {        // k 256..511: h1(t-1)
                    bf16x8 a = *(const bf16x8*)&hBb[nm * 264 + kt * 32 + quad * 8];
                    if (kt & 1) ac1 = __builtin_amdgcn_mfma_f32_16x16x32_bf16(a, wfrag[8 + kt], ac1, 0, 0, 0);
                    else        ac0 = __builtin_amdgcn_mfma_f32_16x16x32_bf16(a, wfrag[8 + kt], ac0, 0, 0, 0);
                }
            }
        }
        f32x4 acc = ac0 + ac1;
#pragma unroll
        for (int r = 0; r < 4; ++r) gl[wave][quad * 4 + r][nm] = acc[r];
        __syncthreads();   // b2

        // ---- cell update; own-slice prefill; tagged publish ----
        {
            float iv = gl[0][bl][cl] + bi;
            float fv = gl[1][bl][cl] + bff;
            float gv = gl[2][bl][cl] + bg;
            float ov = gl[3][bl][cl] + bo;
            float cn = creg * fsigm(fv) + fsigm(iv) * ftanh(gv);
            creg = cn;
            float hn = fsigm(ov) * ftanh(cn);
            unsigned short hbits = __builtin_bit_cast(unsigned short, (bf16)hn);
            hOutS[tid] = hbits;
            (l ? hBb : hAb)[bl * 264 + ms * 16 + cl] = hbits;   // own slice for t+1
            if (l && t == T_ - 1) hf_out[(size_t)(g * 16 + bl) * 256 + gcol] = (bf16)hn;
        }
        __syncthreads();   // b3

        if (tid < 37) {
            int b0i = tid * 7;
            unsigned short v[7];
#pragma unroll
            for (int p = 0; p < 7; ++p) { int idx = b0i + p; v[p] = (idx < 256) ? hOutS[idx] : (unsigned short)0; }
            u32x4 val;
            val[0] = (unsigned)v[0] | ((unsigned)v[1] << 16);
            val[1] = (unsigned)v[2] | ((unsigned)v[3] << 16);
            val[2] = (unsigned)v[4] | ((unsigned)v[5] << 16);
            val[3] = (unsigned)v[6] | ((unsigned)(t + 1) << 16);
            cstore16(outringc + ((size_t)(t & 7)) * SLOT_BYTES + g * GRP_BYTES + ms * SLICE_BYTES + tid * 16, val);
        }
        // no drain needed: tags self-validate; next epilogue is 2+ barriers away
    }
}

// Backward = ONE step with zero h,c per layer.
__global__ __launch_bounds__(256) void bwd_kernel(
    int layer, const float* __restrict__ x, const bf16* __restrict__ inbf,
    const bf16* __restrict__ Wxbf, const float* __restrict__ bs,
    bf16* __restrict__ hb_out) {
    int lwg = blockIdx.x;
    int bt = lwg >> 4, hc = lwg & 15;
    int b0 = bt * 32;
    int tid = threadIdx.x, wave = tid >> 6, lane = tid & 63;
    int nm = lane & 15, quad = lane >> 4;

    __shared__ float gl[4][32][17];
    f32x4 acc0 = {0.f, 0.f, 0.f, 0.f};
    f32x4 acc1 = {0.f, 0.f, 0.f, 0.f};

    int wrow = wave * 256 + hc * 16 + nm;
    const bf16* wxp = Wxbf + (size_t)wrow * H_ + quad * 8;
    int bA0 = b0 + nm, bA1 = b0 + 16 + nm;

    if (layer == 0) {
        const float* xp0 = x + ((size_t)bA0 * T_ + (T_ - 1)) * H_ + quad * 8;
        const float* xp1 = x + ((size_t)bA1 * T_ + (T_ - 1)) * H_ + quad * 8;
#pragma unroll
        for (int ks = 0; ks < 8; ++ks) {
            int k0 = ks * 32;
            bf16x8 bx = *(const bf16x8*)(wxp + k0);
            f32x8 xf0 = *(const f32x8*)(xp0 + k0);
            f32x8 xf1 = *(const f32x8*)(xp1 + k0);
            bf16x8 a0, a1;
#pragma unroll
            for (int j = 0; j < 8; ++j) { a0[j] = (bf16)xf0[j]; a1[j] = (bf16)xf1[j]; }
            acc0 = __builtin_amdgcn_mfma_f32_16x16x32_bf16(a0, bx, acc0, 0, 0, 0);
            acc1 = __builtin_amdgcn_mfma_f32_16x16x32_bf16(a1, bx, acc1, 0, 0, 0);
        }
    } else {
        const bf16* ip0 = inbf + (size_t)bA0 * H_ + quad * 8;
        const bf16* ip1 = inbf + (size_t)bA1 * H_ + quad * 8;
#pragma unroll
        for (int ks = 0; ks < 8; ++ks) {
            int k0 = ks * 32;
            bf16x8 bx = *(const bf16x8*)(wxp + k0);
            bf16x8 a0 = *(const bf16x8*)(ip0 + k0);
            bf16x8 a1 = *(const bf16x8*)(ip1 + k0);
            acc0 = __builtin_amdgcn_mfma_f32_16x16x32_bf16(a0, bx, acc0, 0, 0, 0);
            acc1 = __builtin_amdgcn_mfma_f32_16x16x32_bf16(a1, bx, acc1, 0, 0, 0);
        }
    }
#pragma unroll
    for (int r = 0; r < 4; ++r) {
        gl[wave][quad * 4 + r][nm]      = acc0[r];
        gl[wave][16 + quad * 4 + r][nm] = acc1[r];
    }
    __syncthreads();
#pragma unroll
    for (int p = tid; p < 512; p += 256) {
        int bl = p >> 4, cl = p & 15;
        int gcol = hc * 16 + cl;
        float iv = gl[0][bl][cl] + bs[gcol];
        float gv = gl[2][bl][cl] + bs[512 + gcol];
        float ov = gl[3][bl][cl] + bs[768 + gcol];
        float cn = sigm(iv) * tanhf(gv);
        hb_out[(size_t)(b0 + bl) * H_ + gcol] = (bf16)(sigm(ov) * tanhf(cn));
    }
}

__global__ __launch_bounds__(256) void fc_kernel(
    const bf16* __restrict__ hf, const bf16* __restrict__ hb,
    const float* __restrict__ fcW, const float* __restrict__ fcb,
    float* __restrict__ out) {
    int b = blockIdx.x, o = threadIdx.x;
    __shared__ float v[512];
    v[o]       = (float)hf[(size_t)b * H_ + o];
    v[256 + o] = (float)hb[(size_t)b * H_ + o];
    __syncthreads();
    const float4* wr = (const float4*)(fcW + (size_t)o * 512);
    float sum = fcb[o];
#pragma unroll 4
    for (int j4 = 0; j4 < 128; ++j4) {
        float4 w = wr[j4];
        const float* vv = &v[j4 * 4];
        sum += w.x * vv[0] + w.y * vv[1] + w.z * vv[2] + w.w * vv[3];
    }
    out[(size_t)b * 256 + o] = sum;
}

extern "C" void kernel_launch(void* const* d_in, const int* in_sizes, int n_in,
                              void* d_out, int out_size, void* d_ws, size_t ws_size,
                              hipStream_t stream) {
    const float* x   = (const float*)d_in[0];
    const float* Wxh = (const float*)d_in[1];
    const float* Whh = (const float*)d_in[2];
    const float* bxh = (const float*)d_in[3];
    const float* bhh = (const float*)d_in[4];
    const float* fcW = (const float*)d_in[5];
    const float* fcb = (const float*)d_in[6];
    float* out = (float*)d_out;

    char* ws = (char*)d_ws;
    bf16*  Wxbf   = (bf16*)ws;                       // 1,048,576
    bf16*  Whbf   = (bf16*)(ws + 1048576);           // 1,048,576
    float* bsum   = (float*)(ws + 2097152);          //     8,192
    char*  ring0  = ws + 2105344;                    //   655,360 (8 slots)
    char*  ring1  = ws + 2760704;                    //   655,360
    int*   prog   = (int*)(ws + 3416064);            //     1,024
    bf16*  hf_out = (bf16*)(ws + 3417088);           //    65,536
    bf16*  hb0    = (bf16*)(ws + 3482624);           //    65,536
    bf16*  hb1    = (bf16*)(ws + 3548160);           //    65,536

    // rings need NO init (tags self-validate; 0xAAAA poison never matches t+1<=2048)
    hipMemsetAsync(prog, 0, 1024, stream);
    prep_kernel<<<2048, 256, 0, stream>>>(Wxh, Whh, bxh, bhh, Wxbf, Whbf, bsum);

    lstm_persist<<<256, 256, 0, stream>>>(x, Wxbf, Whbf, bsum, ring0, ring1, prog, hf_out);

    bwd_kernel<<<64, 256, 0, stream>>>(0, x, nullptr, Wxbf, bsum, hb0);
    bwd_kernel<<<64, 256, 0, stream>>>(1, x, hb0, Wxbf + (size_t)G4_ * H_, bsum + G4_, hb1);

    fc_kernel<<<128, 256, 0, stream>>>(hf_out, hb1, fcW, fcb, out);
}